// Round 7
// baseline (286.806 us; speedup 1.0000x reference)
//
#include <hip/hip_runtime.h>

// CELoss_Marginal_Smooth: B=4194304 rows, C=12 classes, fp32 -> scalar loss.
// R6 post-mortem: persistent waves + wave-private LDS slices + reg double
// buffer cut kernel ~86 -> ~66us (bench 286 -> 266). Still ~2x above the
// ~32us streaming floor. R7 changes:
//  (1) drop nontemporal hints — R1-R4 FETCH_SIZE=106MB proved L3 retains
//      ~half the input across replays; nt marks lines evict-first and
//      forfeits that free bandwidth.
//  (2) prefetch depth 2 (3-slot rotating register buffer) — with in-order
//      vmcnt, depth 1 lets the per-wave pipe bubble under loaded-HBM
//      latency; depth 2 keeps ~8 loads continuously outstanding per wave.

#define CLS 12
#define ALPHA_F 0.6f
#define ROWS_PER_TILE 256
#define TILES 8
#define ROWS_PER_BLOCK (ROWS_PER_TILE * TILES)   // 2048

typedef float floatx4 __attribute__((ext_vector_type(4)));

// att[i] = 1 / (# of 8-connected neighbors of cell i in a 3x4 grid)
__device__ __constant__ float ATT_TAB[CLS] = {
    1.0f/3.0f, 1.0f/5.0f, 1.0f/5.0f, 1.0f/3.0f,
    1.0f/5.0f, 1.0f/8.0f, 1.0f/8.0f, 1.0f/5.0f,
    1.0f/3.0f, 1.0f/5.0f, 1.0f/5.0f, 1.0f/3.0f
};

__device__ __forceinline__ float row_loss_compute(floatx4 f0, floatx4 f1, floatx4 f2, int t)
{
    float x[CLS] = { f0.x, f0.y, f0.z, f0.w,
                     f1.x, f1.y, f1.z, f1.w,
                     f2.x, f2.y, f2.z, f2.w };

    float m = x[0];
    #pragma unroll
    for (int j = 1; j < CLS; ++j) m = fmaxf(m, x[j]);

    float se = 0.0f, rs = 0.0f;
    #pragma unroll
    for (int j = 0; j < CLS; ++j) {
        se += __expf(x[j] - m);
        rs += x[j];
    }
    float lse = m + __logf(se);

    float xt = x[0];
    #pragma unroll
    for (int j = 1; j < CLS; ++j) xt = (t == j) ? x[j] : xt;

    float logp_t  = xt - lse;
    float row_sum = rs - (float)CLS * lse;
    float att     = ATT_TAB[t];

    return -ALPHA_F * logp_t
           - (1.0f - ALPHA_F) * (att * (row_sum - logp_t) + logp_t);
}

__global__ __launch_bounds__(256)
void ce_ms_partial_kernel(const float* __restrict__ outputs,
                          const int*   __restrict__ targets,
                          float* __restrict__ partial,
                          int B, float inv_b)
{
    __shared__ float tile[256 * CLS];        // 12 KB: four wave-private 3 KB slices
    __shared__ float warp_part[4];

    const int t    = threadIdx.x;
    const int lane = t & 63;
    const int wave = t >> 6;
    floatx4* ws4 = reinterpret_cast<floatx4*>(tile) + wave * 192;  // 192 float4 per wave

    const floatx4* gp = reinterpret_cast<const floatx4*>(outputs);
    float acc = 0.0f;

    const long long blk_row0 = (long long)blockIdx.x * ROWS_PER_BLOCK;

    if (blk_row0 + ROWS_PER_BLOCK <= (long long)B) {
        // Fast path: this wave owns rows [wrow + k*256, +64) for k=0..7.
        const long long wrow = blk_row0 + wave * 64;

        // 3-slot rotating register buffer, prefetch depth 2.
        floatx4 b0[3], b1[3], b2[3];
        int     bt[3];

        #pragma unroll
        for (int s = 0; s < 2; ++s) {
            long long r  = wrow + (long long)s * ROWS_PER_TILE;
            long long fb = r * 3;
            b0[s] = gp[fb + lane];
            b1[s] = gp[fb + 64 + lane];
            b2[s] = gp[fb + 128 + lane];
            bt[s] = targets[r + lane];
        }

        #pragma unroll
        for (int k = 0; k < TILES; ++k) {
            const int cur = k % 3;
            if (k + 2 < TILES) {
                // Issue tile k+2's loads BEFORE consuming tile k: ~8 loads
                // continuously outstanding per wave (in-order vmcnt never
                // drains below tile k+1's set).
                const int nxt = (k + 2) % 3;
                long long r  = wrow + (long long)(k + 2) * ROWS_PER_TILE;
                long long fb = r * 3;
                b0[nxt] = gp[fb + lane];
                b1[nxt] = gp[fb + 64 + lane];
                b2[nxt] = gp[fb + 128 + lane];
                bt[nxt] = targets[r + lane];
            }
            // Wave-private LDS transpose: no __syncthreads needed (intra-wave
            // DS ops are ordered; slices are disjoint across waves).
            ws4[lane]       = b0[cur];
            ws4[lane + 64]  = b1[cur];
            ws4[lane + 128] = b2[cur];
            floatx4 f0  = ws4[lane * 3 + 0];
            floatx4 f1  = ws4[lane * 3 + 1];
            floatx4 f2v = ws4[lane * 3 + 2];
            acc += row_loss_compute(f0, f1, f2v, bt[cur]);
        }
    } else {
        // Tail path (unused when ROWS_PER_BLOCK divides B): direct strided loads.
        for (int k = 0; k < TILES; ++k) {
            long long row = blk_row0 + (long long)k * ROWS_PER_TILE + t;
            if (row < (long long)B) {
                const floatx4* p = gp + row * 3;
                acc += row_loss_compute(p[0], p[1], p[2], targets[row]);
            }
        }
    }

    acc *= inv_b;

    // wave64 butterfly reduce
    #pragma unroll
    for (int off = 32; off > 0; off >>= 1)
        acc += __shfl_down(acc, off, 64);

    if ((t & 63) == 0) warp_part[wave] = acc;
    __syncthreads();
    if (t == 0)
        partial[blockIdx.x] = warp_part[0] + warp_part[1] + warp_part[2] + warp_part[3];
}

__global__ __launch_bounds__(256)
void ce_ms_final_kernel(const float* __restrict__ partial, float* __restrict__ out, int n)
{
    const int t = threadIdx.x;
    float acc = 0.0f;
    for (int i = t; i < n; i += 256)
        acc += partial[i];

    #pragma unroll
    for (int off = 32; off > 0; off >>= 1)
        acc += __shfl_down(acc, off, 64);

    __shared__ float warp_part[4];
    const int wave = t >> 6;
    if ((t & 63) == 0) warp_part[wave] = acc;
    __syncthreads();
    if (t == 0)
        out[0] = warp_part[0] + warp_part[1] + warp_part[2] + warp_part[3];
}

extern "C" void kernel_launch(void* const* d_in, const int* in_sizes, int n_in,
                              void* d_out, int out_size, void* d_ws, size_t ws_size,
                              hipStream_t stream)
{
    const float* outputs = (const float*)d_in[0];
    const int*   targets = (const int*)d_in[1];
    float*       out     = (float*)d_out;
    float*       partial = (float*)d_ws;

    const int B = in_sizes[1];
    const float inv_b = 1.0f / (float)B;

    const int grid = (int)(((long long)B + ROWS_PER_BLOCK - 1) / ROWS_PER_BLOCK);  // 2048
    ce_ms_partial_kernel<<<grid, 256, 0, stream>>>(outputs, targets, partial, B, inv_b);
    ce_ms_final_kernel<<<1, 256, 0, stream>>>(partial, out, grid);
}

// Round 8
// 265.929 us; speedup vs baseline: 1.0785x; 1.0785x over previous
//
#include <hip/hip_runtime.h>

// CELoss_Marginal_Smooth: B=4194304 rows, C=12 classes, fp32 -> scalar loss.
// R7 post-mortem: all non-nt variants (R2/R3/R4/R7) tie at ~287us bench
// regardless of access pattern / occupancy / prefetch depth; the single
// 266us run (R6) had __builtin_nontemporal_load. => nt is the active
// ingredient (~20us): single-pass reads bypassing L2 allocation avoid
// paying for the lines the 805MB restore-fill just dirtied. Depth-2
// prefetch was at best neutral. This round: exact R6 configuration
// (nt + depth-1 register double-buffer + wave-private LDS slices, no
// in-loop barriers) to confirm reproducibility of 266.

#define CLS 12
#define ALPHA_F 0.6f
#define ROWS_PER_TILE 256
#define TILES 8
#define ROWS_PER_BLOCK (ROWS_PER_TILE * TILES)   // 2048

typedef float floatx4 __attribute__((ext_vector_type(4)));

// att[i] = 1 / (# of 8-connected neighbors of cell i in a 3x4 grid)
__device__ __constant__ float ATT_TAB[CLS] = {
    1.0f/3.0f, 1.0f/5.0f, 1.0f/5.0f, 1.0f/3.0f,
    1.0f/5.0f, 1.0f/8.0f, 1.0f/8.0f, 1.0f/5.0f,
    1.0f/3.0f, 1.0f/5.0f, 1.0f/5.0f, 1.0f/3.0f
};

__device__ __forceinline__ float row_loss_compute(floatx4 f0, floatx4 f1, floatx4 f2, int t)
{
    float x[CLS] = { f0.x, f0.y, f0.z, f0.w,
                     f1.x, f1.y, f1.z, f1.w,
                     f2.x, f2.y, f2.z, f2.w };

    float m = x[0];
    #pragma unroll
    for (int j = 1; j < CLS; ++j) m = fmaxf(m, x[j]);

    float se = 0.0f, rs = 0.0f;
    #pragma unroll
    for (int j = 0; j < CLS; ++j) {
        se += __expf(x[j] - m);
        rs += x[j];
    }
    float lse = m + __logf(se);

    float xt = x[0];
    #pragma unroll
    for (int j = 1; j < CLS; ++j) xt = (t == j) ? x[j] : xt;

    float logp_t  = xt - lse;
    float row_sum = rs - (float)CLS * lse;
    float att     = ATT_TAB[t];

    return -ALPHA_F * logp_t
           - (1.0f - ALPHA_F) * (att * (row_sum - logp_t) + logp_t);
}

__global__ __launch_bounds__(256)
void ce_ms_partial_kernel(const float* __restrict__ outputs,
                          const int*   __restrict__ targets,
                          float* __restrict__ partial,
                          int B, float inv_b)
{
    __shared__ float tile[256 * CLS];        // 12 KB: four wave-private 3 KB slices
    __shared__ float warp_part[4];

    const int t    = threadIdx.x;
    const int lane = t & 63;
    const int wave = t >> 6;
    floatx4* ws4 = reinterpret_cast<floatx4*>(tile) + wave * 192;  // 192 float4 per wave

    const floatx4* gp = reinterpret_cast<const floatx4*>(outputs);
    float acc = 0.0f;

    const long long blk_row0 = (long long)blockIdx.x * ROWS_PER_BLOCK;

    if (blk_row0 + ROWS_PER_BLOCK <= (long long)B) {
        // Fast path: this wave owns rows [wrow + k*256, +64) for k=0..7.
        const long long wrow = blk_row0 + wave * 64;

        // Prefetch tile 0 (coalesced, lane-consecutive float4, nontemporal).
        long long fb = wrow * 3;
        floatx4 n0 = __builtin_nontemporal_load(gp + fb + lane);
        floatx4 n1 = __builtin_nontemporal_load(gp + fb + 64 + lane);
        floatx4 n2 = __builtin_nontemporal_load(gp + fb + 128 + lane);
        int     nt = __builtin_nontemporal_load(targets + wrow + lane);

        #pragma unroll
        for (int k = 0; k < TILES; ++k) {
            floatx4 c0 = n0, c1 = n1, c2 = n2;
            int     ct = nt;
            if (k + 1 < TILES) {
                // Issue next tile's loads BEFORE consuming this tile ->
                // VMEM pipe never drains (compiler emits partial vmcnt waits).
                long long r2  = wrow + (long long)(k + 1) * ROWS_PER_TILE;
                long long f2b = r2 * 3;
                n0 = __builtin_nontemporal_load(gp + f2b + lane);
                n1 = __builtin_nontemporal_load(gp + f2b + 64 + lane);
                n2 = __builtin_nontemporal_load(gp + f2b + 128 + lane);
                nt = __builtin_nontemporal_load(targets + r2 + lane);
            }
            // Wave-private LDS transpose: no __syncthreads needed (intra-wave
            // DS ops are ordered; slices are disjoint across waves).
            ws4[lane]       = c0;
            ws4[lane + 64]  = c1;
            ws4[lane + 128] = c2;
            floatx4 f0  = ws4[lane * 3 + 0];
            floatx4 f1  = ws4[lane * 3 + 1];
            floatx4 f2v = ws4[lane * 3 + 2];
            acc += row_loss_compute(f0, f1, f2v, ct);
        }
    } else {
        // Tail path (unused when ROWS_PER_BLOCK divides B): direct strided loads.
        for (int k = 0; k < TILES; ++k) {
            long long row = blk_row0 + (long long)k * ROWS_PER_TILE + t;
            if (row < (long long)B) {
                const floatx4* p = gp + row * 3;
                acc += row_loss_compute(p[0], p[1], p[2], targets[row]);
            }
        }
    }

    acc *= inv_b;

    // wave64 butterfly reduce
    #pragma unroll
    for (int off = 32; off > 0; off >>= 1)
        acc += __shfl_down(acc, off, 64);

    if ((t & 63) == 0) warp_part[wave] = acc;
    __syncthreads();
    if (t == 0)
        partial[blockIdx.x] = warp_part[0] + warp_part[1] + warp_part[2] + warp_part[3];
}

__global__ __launch_bounds__(256)
void ce_ms_final_kernel(const float* __restrict__ partial, float* __restrict__ out, int n)
{
    const int t = threadIdx.x;
    float acc = 0.0f;
    for (int i = t; i < n; i += 256)
        acc += partial[i];

    #pragma unroll
    for (int off = 32; off > 0; off >>= 1)
        acc += __shfl_down(acc, off, 64);

    __shared__ float warp_part[4];
    const int wave = t >> 6;
    if ((t & 63) == 0) warp_part[wave] = acc;
    __syncthreads();
    if (t == 0)
        out[0] = warp_part[0] + warp_part[1] + warp_part[2] + warp_part[3];
}

extern "C" void kernel_launch(void* const* d_in, const int* in_sizes, int n_in,
                              void* d_out, int out_size, void* d_ws, size_t ws_size,
                              hipStream_t stream)
{
    const float* outputs = (const float*)d_in[0];
    const int*   targets = (const int*)d_in[1];
    float*       out     = (float*)d_out;
    float*       partial = (float*)d_ws;

    const int B = in_sizes[1];
    const float inv_b = 1.0f / (float)B;

    const int grid = (int)(((long long)B + ROWS_PER_BLOCK - 1) / ROWS_PER_BLOCK);  // 2048
    ce_ms_partial_kernel<<<grid, 256, 0, stream>>>(outputs, targets, partial, B, inv_b);
    ce_ms_final_kernel<<<1, 256, 0, stream>>>(partial, out, grid);
}